// Round 10
// baseline (130.211 us; speedup 1.0000x reference)
//
#include <hip/hip_runtime.h>
#include <hip/hip_bf16.h>

typedef __attribute__((ext_vector_type(8))) short bf16x8;
typedef __attribute__((ext_vector_type(4))) float f32x4;
typedef unsigned short u16;

#define NEG_INF (-__builtin_inff())

// async global->LDS, 16B per lane. LDS dest must be wave-uniform (HW adds lane*16).
__device__ __forceinline__ void gload16(const void* g, void* l) {
  __builtin_amdgcn_global_load_lds(
      (const __attribute__((address_space(1))) void*)g,
      (__attribute__((address_space(3))) void*)l, 16, 0, 0);
}

__device__ __forceinline__ u16 f2b(float f) {
  union { float f; unsigned u; } v;
  v.f = f;
  unsigned r = v.u + 0x7fff + ((v.u >> 16) & 1);  // RNE
  return (u16)(r >> 16);
}

// ---------------- fp32 -> bf16 elementwise (x), 4 elems/thread -------------
__global__ __launch_bounds__(256) void cvt_f2b_kernel(
    const float* __restrict__ in, u16* __restrict__ out, int n4) {
  int i = blockIdx.x * 256 + threadIdx.x;
  if (i >= n4) return;
  float4 v = ((const float4*)in)[i];
  ushort2 a = {f2b(v.x), f2b(v.y)}, b = {f2b(v.z), f2b(v.w)};
  ((ushort2*)out)[i * 2] = a;
  ((ushort2*)out)[i * 2 + 1] = b;
}

// ------- batched transpose + cvt: dst[bz][c][r] = bf16(src[bz][r][c]) ------
__global__ __launch_bounds__(256) void transpose_f2b(
    const float* __restrict__ src, u16* __restrict__ dst, int R, int C) {
  __shared__ u16 t[32][33];
  int c0 = blockIdx.x * 32, r0 = blockIdx.y * 32;
  const float* s = src + (size_t)blockIdx.z * R * C;
  u16* d = dst + (size_t)blockIdx.z * R * C;
  for (int i = threadIdx.y; i < 32; i += 8)
    t[i][threadIdx.x] = f2b(s[(size_t)(r0 + i) * C + c0 + threadIdx.x]);
  __syncthreads();
  for (int i = threadIdx.y; i < 32; i += 8)
    d[(size_t)(c0 + i) * R + r0 + threadIdx.x] = t[threadIdx.x][i];
}

// ------- 128x128x32 bf16 GEMM mainloop, double-buffered + counted vmcnt ----
// A row-major [M][K] bf16, Bt row-major [N][K] bf16. 4 waves, each owns a
// 64x64 quadrant (4x4 frags of 16x16). acc: C[row=(lane>>4)*4+r][col=lane&15].
// AsB/BsB: 2 x 8KB buffers each (32KB total LDS).
__device__ __forceinline__ void gemm_mainloop_128(
    const __hip_bfloat16* __restrict__ A, const __hip_bfloat16* __restrict__ Bt,
    int K, int m0, int n0, f32x4 acc[4][4], char* AsB, char* BsB) {
  const int tid = threadIdx.x;
  const int wave = tid >> 6, lane = tid & 63;
  const int lhi = lane >> 4, llo = lane & 15;
  const int wr = wave >> 1, wc = wave & 1;
  f32x4 z = {0.f, 0.f, 0.f, 0.f};
#pragma unroll
  for (int i = 0; i < 4; i++)
#pragma unroll
    for (int j = 0; j < 4; j++) acc[i][j] = z;

#define GSTAGE(c, kk)                                                          \
  {                                                                            \
    char* AsW = AsB + (c)*8192;                                                \
    char* BsW = BsB + (c)*8192;                                                \
    _Pragma("unroll") for (int i = 0; i < 2; i++) {                            \
      int cb = i * 256 + wave * 64;                                            \
      int cq = cb + lane;                                                      \
      gload16(A + ((size_t)(m0 + (cq >> 2)) * K + (kk) + (cq & 3) * 8),        \
              AsW + cb * 16);                                                  \
      gload16(Bt + ((size_t)(n0 + (cq >> 2)) * K + (kk) + (cq & 3) * 8),       \
              BsW + cb * 16);                                                  \
    }                                                                          \
  }

  GSTAGE(0, 0);
  int cur = 0;
  const int nk = K >> 5;
  for (int t = 0; t < nk; t++) {
    if (t + 1 < nk) {
      GSTAGE(cur ^ 1, (t + 1) * 32);
      asm volatile("s_waitcnt vmcnt(4)" ::: "memory");
    } else {
      asm volatile("s_waitcnt vmcnt(0)" ::: "memory");
    }
    __builtin_amdgcn_s_barrier();
    __builtin_amdgcn_sched_barrier(0);

    const char* Ar = AsB + cur * 8192;
    const char* Br = BsB + cur * 8192;
    bf16x8 a[4], b[4];
#pragma unroll
    for (int m4 = 0; m4 < 4; m4++)
      a[m4] = *(const bf16x8*)(Ar + (wr * 64 + m4 * 16 + llo) * 64 + lhi * 16);
#pragma unroll
    for (int n4 = 0; n4 < 4; n4++)
      b[n4] = *(const bf16x8*)(Br + (wc * 64 + n4 * 16 + llo) * 64 + lhi * 16);
#pragma unroll
    for (int m4 = 0; m4 < 4; m4++)
#pragma unroll
      for (int n4 = 0; n4 < 4; n4++)
        acc[m4][n4] =
            __builtin_amdgcn_mfma_f32_16x16x32_bf16(a[m4], b[n4], acc[m4][n4], 0, 0, 0);
    __builtin_amdgcn_sched_barrier(0);
    __builtin_amdgcn_s_barrier();
    cur ^= 1;
  }
#undef GSTAGE
}

// ------------- GEMM1: kqv = x @ WkqvT^T + bkqv, scatter to K/Q/Vt ----------
// Q pre-scaled by 0.125 * log2(e) (attn works in exp2 domain).
__global__ __launch_bounds__(256) void kqv_gemm(
    const __hip_bfloat16* __restrict__ x, const __hip_bfloat16* __restrict__ WT,
    const float* __restrict__ bkqv, __hip_bfloat16* __restrict__ Qb,
    __hip_bfloat16* __restrict__ Kb, __hip_bfloat16* __restrict__ Vt) {
  __shared__ __align__(16) char As[16384];
  __shared__ __align__(16) char Bs[16384];
  const int m0 = blockIdx.y * 128, n0 = blockIdx.x * 128;
  f32x4 acc[4][4];
  gemm_mainloop_128(x, WT, 1024, m0, n0, acc, As, Bs);

  const int tid = threadIdx.x, wave = tid >> 6, lane = tid & 63;
  const int lhi = lane >> 4, llo = lane & 15;
  const int wr = wave >> 1, wc = wave & 1;
#pragma unroll
  for (int m4 = 0; m4 < 4; m4++)
#pragma unroll
    for (int n4 = 0; n4 < 4; n4++)
#pragma unroll
      for (int r = 0; r < 4; r++) {
        int mg = m0 + wr * 64 + m4 * 16 + lhi * 4 + r;
        int ng = n0 + wc * 64 + n4 * 16 + llo;
        int b = mg >> 11, s = mg & 2047;
        int h = ng / 192, f = ng % 192;
        float v = acc[m4][n4][r] + bkqv[h * 192 + f];
        int chunk = f >> 6, d = f & 63;
        size_t bh = (size_t)(b * 16 + h);
        if (chunk == 0)
          Kb[(bh * 2048 + s) * 64 + d] = __float2bfloat16(v);
        else if (chunk == 1)
          Qb[(bh * 2048 + s) * 64 + d] = __float2bfloat16(v * 0.180336880f);
        else
          Vt[(bh * 64 + d) * 2048 + s] = __float2bfloat16(v);
      }
}

// ------------------- causal flash attention, D=64 --------------------------
// 1 block = one (b,h) and a PAIR of 64-row q-tiles (qa=31-i, qb=i) -> 33
// KB=64 key-tiles per block. Swapped QK^T (mfma(K,Q)): each lane owns q=llo
// with 16 local scores -> scalar m/l state, 2-shfl row reduce, packed b64
// P-writes, defer-max rescale (THR=5 in log2 units), exp2 softmax.
__global__ __launch_bounds__(256) void attn_kernel(
    const __hip_bfloat16* __restrict__ Qb, const __hip_bfloat16* __restrict__ Kb,
    const __hip_bfloat16* __restrict__ Vt, __hip_bfloat16* __restrict__ SA) {
  __shared__ __align__(16) char lds[40960];  // Ks 2x8K | Vs 2x8K | Ps 4x2K
  const int bx0 = blockIdx.x;
  const int bx = (bx0 & 7) * 64 + (bx0 >> 3);  // XCD swizzle (512 % 8 == 0)
  const int bh = bx >> 4;
  const int ip = bx & 15;
  const int qa = 31 - ip, qbt = ip;   // heavy + light q-tile
  const int nta = qa + 1, nt = nta + qbt + 1;  // 33 tiles
  const int b = bh >> 4, h = bh & 15;
  const int tid = threadIdx.x, wave = tid >> 6, lane = tid & 63;
  const int lhi = lane >> 4, llo = lane & 15;
  const int lhi4 = lhi * 4;

  // Q fragments for both passes (Q pre-scaled by 0.125*log2e in kqv_gemm)
  const __hip_bfloat16* qpA =
      Qb + ((size_t)bh * 2048 + qa * 64 + wave * 16 + llo) * 64 + lhi * 8;
  const __hip_bfloat16* qpB =
      Qb + ((size_t)bh * 2048 + qbt * 64 + wave * 16 + llo) * 64 + lhi * 8;
  bf16x8 qA0 = *(const bf16x8*)qpA, qA1 = *(const bf16x8*)(qpA + 32);
  bf16x8 qB0 = *(const bf16x8*)qpB, qB1 = *(const bf16x8*)(qpB + 32);
  bf16x8 q0 = qA0, q1 = qA1;

  const char* Kg = (const char*)(Kb + (size_t)bh * 2048 * 64);
  const char* Vg = (const char*)(Vt + (size_t)bh * 64 * 2048);
  char* PsB = lds + 32768 + wave * 2048;

  f32x4 z = {0.f, 0.f, 0.f, 0.f};
  f32x4 o[4];
  float m_s = NEG_INF, l_s = 0.f;
#pragma unroll
  for (int i = 0; i < 4; i++) o[i] = z;
  int qg = qa * 64 + wave * 16 + llo;     // masking row (this lane's q)
  int qg0 = qa * 64 + wave * 16 + lhi4;   // output row base (PV layout)

  // ---- stage tile (k0 in keys) into buffer c (0/1): 4 gload16/thread ----
#define STAGE(c, k0)                                                          \
  {                                                                           \
    char* KsW = lds + (c)*8192;                                               \
    char* VsW = lds + 16384 + (c)*8192;                                       \
    _Pragma("unroll") for (int i = 0; i < 2; i++) {                           \
      int ch = i * 256 + tid;                                                 \
      int soff = (ch * 16) ^ (((ch >> 3) & 7) << 4);                          \
      gload16(Kg + (size_t)(k0)*128 + soff, KsW + (i * 256 + wave * 64) * 16);\
      int dd = ch >> 3, c8 = ch & 7;                                          \
      int boff = (c8 * 16) ^ ((dd & 7) << 4);                                 \
      gload16(Vg + (size_t)dd * 4096 + (size_t)(k0)*2 + boff,                 \
              VsW + (i * 256 + wave * 64) * 16);                              \
    }                                                                         \
  }

  STAGE(0, 0);
  int cur = 0;

  for (int T = 0; T < nt; T++) {
    const int Tn = T + 1;
    if (Tn < nt) {
      const int k0n = (Tn < nta ? Tn : Tn - nta) * 64;
      STAGE(cur ^ 1, k0n);
      asm volatile("s_waitcnt vmcnt(4)" ::: "memory");
    } else {
      asm volatile("s_waitcnt vmcnt(0)" ::: "memory");
    }
    __builtin_amdgcn_s_barrier();
    __builtin_amdgcn_sched_barrier(0);

    const int k0 = (T < nta ? T : T - nta) * 64;
    const bool masked = (T == nta - 1) || (T == nt - 1);
    const char* KsB = lds + cur * 8192;
    const char* VsB = lds + 16384 + cur * 8192;

    // ---- QK^T swapped: s[j] = C[key=j*16+lhi4+r][q=llo] ----
    f32x4 s[4] = {z, z, z, z};
#pragma unroll
    for (int j = 0; j < 4; j++) {
      const int row = j * 16 + llo;
      const int rx = (row & 7) << 4;
      bf16x8 bk0 = *(const bf16x8*)(KsB + ((row * 128 + lhi * 16) ^ rx));
      bf16x8 bk1 = *(const bf16x8*)(KsB + ((row * 128 + 64 + lhi * 16) ^ rx));
      s[j] = __builtin_amdgcn_mfma_f32_16x16x32_bf16(bk0, q0, s[j], 0, 0, 0);
      s[j] = __builtin_amdgcn_mfma_f32_16x16x32_bf16(bk1, q1, s[j], 0, 0, 0);
    }

    // ---- in-lane online softmax (lane owns q=llo; 16 scores local) ----
    if (masked) {
#pragma unroll
      for (int j = 0; j < 4; j++)
#pragma unroll
        for (int r = 0; r < 4; r++)
          if (k0 + j * 16 + lhi4 + r > qg) s[j][r] = NEG_INF;
    }
    float pmax = s[0][0];
#pragma unroll
    for (int j = 0; j < 4; j++)
#pragma unroll
      for (int r = 0; r < 4; r++) pmax = fmaxf(pmax, s[j][r]);
    pmax = fmaxf(pmax, __shfl_xor(pmax, 16));
    pmax = fmaxf(pmax, __shfl_xor(pmax, 32));
    if (!__all(pmax - m_s <= 5.0f)) {  // defer-max: rescale rarely
      const float mn = fmaxf(m_s, pmax);
      const float sc = __builtin_exp2f(m_s - mn);
      m_s = mn;
      l_s *= sc;
#pragma unroll
      for (int r = 0; r < 4; r++) {
        const float scr = __shfl(sc, lhi4 + r);
#pragma unroll
        for (int n4 = 0; n4 < 4; n4++) o[n4][r] *= scr;
      }
    }
    const int px = (llo & 7) << 4;
    float ps = 0.f;
#pragma unroll
    for (int j = 0; j < 4; j++) {
      ushort4 pw;
#pragma unroll
      for (int r = 0; r < 4; r++) {
        const float p = __builtin_exp2f(s[j][r] - m_s);
        ps += p;
        ((__hip_bfloat16*)&pw)[r] = __float2bfloat16(p);
      }
      *(ushort4*)(PsB + ((llo * 128 + j * 32 + lhi * 8) ^ px)) = pw;
    }
    l_s += ps;

    // ---- PV: o[n4] += P(16x64) . V^T ----
    {
      bf16x8 ap0 = *(const bf16x8*)(PsB + ((llo * 128 + lhi * 16) ^ px));
      bf16x8 ap1 = *(const bf16x8*)(PsB + ((llo * 128 + 64 + lhi * 16) ^ px));
#pragma unroll
      for (int n4 = 0; n4 < 4; n4++) {
        const int d = n4 * 16 + llo;
        const int dx = (d & 7) << 4;
        bf16x8 bv0 = *(const bf16x8*)(VsB + ((d * 128 + lhi * 16) ^ dx));
        bf16x8 bv1 = *(const bf16x8*)(VsB + ((d * 128 + 64 + lhi * 16) ^ dx));
        o[n4] = __builtin_amdgcn_mfma_f32_16x16x32_bf16(ap0, bv0, o[n4], 0, 0, 0);
        o[n4] = __builtin_amdgcn_mfma_f32_16x16x32_bf16(ap1, bv1, o[n4], 0, 0, 0);
      }
    }
    __builtin_amdgcn_sched_barrier(0);
    __builtin_amdgcn_s_barrier();  // all waves done reading buf[cur]

    if (T == nta - 1) {  // pass A epilogue + reset for pass B
      float l = l_s;
      l += __shfl_xor(l, 16);
      l += __shfl_xor(l, 32);
      const float inv = 1.f / l;
#pragma unroll
      for (int r = 0; r < 4; r++) {
        const float invr = __shfl(inv, lhi4 + r);
        const size_t ob = ((size_t)b * 2048 + qg0 + r) * 1024 + h * 64;
#pragma unroll
        for (int n4 = 0; n4 < 4; n4++)
          SA[ob + n4 * 16 + llo] = __float2bfloat16(o[n4][r] * invr);
      }
#pragma unroll
      for (int i = 0; i < 4; i++) o[i] = z;
      m_s = NEG_INF;
      l_s = 0.f;
      q0 = qB0; q1 = qB1;
      qg = qbt * 64 + wave * 16 + llo;
      qg0 = qbt * 64 + wave * 16 + lhi4;
    }
    cur ^= 1;
  }

  // pass B epilogue
  {
    float l = l_s;
    l += __shfl_xor(l, 16);
    l += __shfl_xor(l, 32);
    const float inv = 1.f / l;
#pragma unroll
    for (int r = 0; r < 4; r++) {
      const float invr = __shfl(inv, lhi4 + r);
      const size_t ob = ((size_t)b * 2048 + qg0 + r) * 1024 + h * 64;
#pragma unroll
      for (int n4 = 0; n4 < 4; n4++)
        SA[ob + n4 * 16 + llo] = __float2bfloat16(o[n4][r] * invr);
    }
  }
#undef STAGE
}

// ------------- GEMM3: out = SA @ Wo + bo  (fp32 OUTPUT) --------------------
__global__ __launch_bounds__(256) void out_gemm(
    const __hip_bfloat16* __restrict__ SA, const __hip_bfloat16* __restrict__ WoT,
    const float* __restrict__ bo, float* __restrict__ out) {
  __shared__ __align__(16) char As[16384];
  __shared__ __align__(16) char Bs[16384];
  const int m0 = blockIdx.y * 128, n0 = blockIdx.x * 128;
  f32x4 acc[4][4];
  gemm_mainloop_128(SA, WoT, 1024, m0, n0, acc, As, Bs);

  const int tid = threadIdx.x, wave = tid >> 6, lane = tid & 63;
  const int lhi = lane >> 4, llo = lane & 15;
  const int wr = wave >> 1, wc = wave & 1;
#pragma unroll
  for (int m4 = 0; m4 < 4; m4++)
#pragma unroll
    for (int n4 = 0; n4 < 4; n4++)
#pragma unroll
      for (int r = 0; r < 4; r++) {
        int mg = m0 + wr * 64 + m4 * 16 + lhi * 4 + r;
        int ng = n0 + wc * 64 + n4 * 16 + llo;
        out[(size_t)mg * 1024 + ng] = acc[m4][n4][r] + bo[ng];
      }
}

extern "C" void kernel_launch(void* const* d_in, const int* in_sizes, int n_in,
                              void* d_out, int out_size, void* d_ws, size_t ws_size,
                              hipStream_t stream) {
  const float* x = (const float*)d_in[0];
  const float* Wkqv = (const float*)d_in[1];
  const float* bkqv = (const float*)d_in[2];
  const float* Wo = (const float*)d_in[3];
  const float* bo = (const float*)d_in[4];
  float* out = (float*)d_out;  // fp32 output (verified R5)

  char* w = (char*)d_ws;
  __hip_bfloat16* WkqvT = (__hip_bfloat16*)(w);            // 3072x1024  (6 MB)
  __hip_bfloat16* WoT = (__hip_bfloat16*)(w + 6291456);    // 1024x1024  (2 MB)
  __hip_bfloat16* Qb = (__hip_bfloat16*)(w + 8388608);     // [B][H][S][64] (8 MB)
  __hip_bfloat16* Kb = (__hip_bfloat16*)(w + 16777216);    // [B][H][S][64] (8 MB)
  __hip_bfloat16* Vt = (__hip_bfloat16*)(w + 25165824);    // [B][H][64][S] (8 MB)
  __hip_bfloat16* SAb = (__hip_bfloat16*)(w + 33554432);   // [B][S][E]     (8 MB)
  __hip_bfloat16* xb = (__hip_bfloat16*)(w + 41943040);    // [B][S][E]     (8 MB)

  cvt_f2b_kernel<<<4096, 256, 0, stream>>>(x, (u16*)xb, 1048576);
  transpose_f2b<<<dim3(6, 32, 16), dim3(32, 8, 1), 0, stream>>>(
      Wkqv, (u16*)WkqvT, 1024, 192);
  transpose_f2b<<<dim3(32, 32, 1), dim3(32, 8, 1), 0, stream>>>(
      Wo, (u16*)WoT, 1024, 1024);
  kqv_gemm<<<dim3(24, 32), 256, 0, stream>>>(xb, WkqvT, bkqv, Qb, Kb, Vt);
  attn_kernel<<<512, 256, 0, stream>>>(Qb, Kb, Vt, SAb);
  out_gemm<<<dim3(8, 32), 256, 0, stream>>>(SAb, WoT, bo, out);
}

// Round 11
// 117.152 us; speedup vs baseline: 1.1115x; 1.1115x over previous
//
#include <hip/hip_runtime.h>
#include <hip/hip_bf16.h>

typedef __attribute__((ext_vector_type(8))) short bf16x8;
typedef __attribute__((ext_vector_type(4))) float f32x4;
typedef unsigned short u16;

#define NEG_INF (-__builtin_inff())

// async global->LDS, 16B per lane. LDS dest must be wave-uniform (HW adds lane*16).
__device__ __forceinline__ void gload16(const void* g, void* l) {
  __builtin_amdgcn_global_load_lds(
      (const __attribute__((address_space(1))) void*)g,
      (__attribute__((address_space(3))) void*)l, 16, 0, 0);
}

__device__ __forceinline__ u16 f2b(float f) {
  union { float f; unsigned u; } v;
  v.f = f;
  unsigned r = v.u + 0x7fff + ((v.u >> 16) & 1);  // RNE
  return (u16)(r >> 16);
}

// ---- fused prep: cvt x -> bf16 | transpose Wkqv | transpose Wo ------------
// grid: [0,4096) cvt | [4096,7168) Wkqv (R=1024,C=192,16 heads) | [7168,8192) Wo
__global__ __launch_bounds__(256) void prep_kernel(
    const float* __restrict__ x, u16* __restrict__ xb,
    const float* __restrict__ Wkqv, u16* __restrict__ WkqvT,
    const float* __restrict__ Wo, u16* __restrict__ WoT) {
  __shared__ u16 t[32][33];
  const int bid = blockIdx.x;
  const int tid = threadIdx.x;
  if (bid < 4096) {  // cvt: 4 floats/thread, 1048576 float4s total
    const int i = bid * 256 + tid;
    float4 v = ((const float4*)x)[i];
    ushort2 a = {f2b(v.x), f2b(v.y)}, b = {f2b(v.z), f2b(v.w)};
    ((ushort2*)xb)[i * 2] = a;
    ((ushort2*)xb)[i * 2 + 1] = b;
    return;
  }
  const int tx = tid & 31, ty = tid >> 5;  // 32x8
  const float* src;
  u16* dst;
  int R, C, bx_, by;
  if (bid < 7168) {  // Wkqv: dst[h][c][r] = bf16(src[h][r][c])
    const int tt = bid - 4096;
    const int bz = tt / 192, rem = tt % 192;
    by = rem / 6; bx_ = rem % 6; R = 1024; C = 192;
    src = Wkqv + (size_t)bz * R * C;
    dst = WkqvT + (size_t)bz * R * C;
  } else {  // Wo
    const int tt = bid - 7168;
    by = tt >> 5; bx_ = tt & 31; R = 1024; C = 1024;
    src = Wo; dst = WoT;
  }
  const int c0 = bx_ * 32, r0 = by * 32;
  for (int i = ty; i < 32; i += 8)
    t[i][tx] = f2b(src[(size_t)(r0 + i) * C + c0 + tx]);
  __syncthreads();
  for (int i = ty; i < 32; i += 8)
    dst[(size_t)(c0 + i) * R + r0 + tx] = t[tx][i];
}

// ------- 128x128x32 bf16 GEMM mainloop, double-buffered + counted vmcnt ----
__device__ __forceinline__ void gemm_mainloop_128(
    const __hip_bfloat16* __restrict__ A, const __hip_bfloat16* __restrict__ Bt,
    int K, int m0, int n0, f32x4 acc[4][4], char* AsB, char* BsB) {
  const int tid = threadIdx.x;
  const int wave = tid >> 6, lane = tid & 63;
  const int lhi = lane >> 4, llo = lane & 15;
  const int wr = wave >> 1, wc = wave & 1;
  f32x4 z = {0.f, 0.f, 0.f, 0.f};
#pragma unroll
  for (int i = 0; i < 4; i++)
#pragma unroll
    for (int j = 0; j < 4; j++) acc[i][j] = z;

#define GSTAGE(c, kk)                                                          \
  {                                                                            \
    char* AsW = AsB + (c)*8192;                                                \
    char* BsW = BsB + (c)*8192;                                                \
    _Pragma("unroll") for (int i = 0; i < 2; i++) {                            \
      int cb = i * 256 + wave * 64;                                            \
      int cq = cb + lane;                                                      \
      gload16(A + ((size_t)(m0 + (cq >> 2)) * K + (kk) + (cq & 3) * 8),        \
              AsW + cb * 16);                                                  \
      gload16(Bt + ((size_t)(n0 + (cq >> 2)) * K + (kk) + (cq & 3) * 8),       \
              BsW + cb * 16);                                                  \
    }                                                                          \
  }

  GSTAGE(0, 0);
  int cur = 0;
  const int nk = K >> 5;
  for (int t = 0; t < nk; t++) {
    if (t + 1 < nk) {
      GSTAGE(cur ^ 1, (t + 1) * 32);
      asm volatile("s_waitcnt vmcnt(4)" ::: "memory");
    } else {
      asm volatile("s_waitcnt vmcnt(0)" ::: "memory");
    }
    __builtin_amdgcn_s_barrier();
    __builtin_amdgcn_sched_barrier(0);

    const char* Ar = AsB + cur * 8192;
    const char* Br = BsB + cur * 8192;
    bf16x8 a[4], b[4];
#pragma unroll
    for (int m4 = 0; m4 < 4; m4++)
      a[m4] = *(const bf16x8*)(Ar + (wr * 64 + m4 * 16 + llo) * 64 + lhi * 16);
#pragma unroll
    for (int n4 = 0; n4 < 4; n4++)
      b[n4] = *(const bf16x8*)(Br + (wc * 64 + n4 * 16 + llo) * 64 + lhi * 16);
#pragma unroll
    for (int m4 = 0; m4 < 4; m4++)
#pragma unroll
      for (int n4 = 0; n4 < 4; n4++)
        acc[m4][n4] =
            __builtin_amdgcn_mfma_f32_16x16x32_bf16(a[m4], b[n4], acc[m4][n4], 0, 0, 0);
    __builtin_amdgcn_sched_barrier(0);
    __builtin_amdgcn_s_barrier();
    cur ^= 1;
  }
#undef GSTAGE
}

// ------- 64x128x32 variant (2 blocks/CU for skinny-M GEMM) -----------------
__device__ __forceinline__ void gemm_mainloop_64x128(
    const __hip_bfloat16* __restrict__ A, const __hip_bfloat16* __restrict__ Bt,
    int K, int m0, int n0, f32x4 acc[2][4], char* AsB, char* BsB) {
  const int tid = threadIdx.x;
  const int wave = tid >> 6, lane = tid & 63;
  const int lhi = lane >> 4, llo = lane & 15;
  const int wr = wave >> 1, wc = wave & 1;
  f32x4 z = {0.f, 0.f, 0.f, 0.f};
#pragma unroll
  for (int i = 0; i < 2; i++)
#pragma unroll
    for (int j = 0; j < 4; j++) acc[i][j] = z;

#define GSTAGE64(c, kk)                                                        \
  {                                                                            \
    char* AsW = AsB + (c)*4096;                                                \
    char* BsW = BsB + (c)*8192;                                                \
    gload16(A + ((size_t)(m0 + (tid >> 2)) * K + (kk) + (tid & 3) * 8),        \
            AsW + (wave * 64) * 16);                                           \
    _Pragma("unroll") for (int i = 0; i < 2; i++) {                            \
      int cb = i * 256 + wave * 64;                                            \
      int cq = cb + lane;                                                      \
      gload16(Bt + ((size_t)(n0 + (cq >> 2)) * K + (kk) + (cq & 3) * 8),       \
              BsW + cb * 16);                                                  \
    }                                                                          \
  }

  GSTAGE64(0, 0);
  int cur = 0;
  const int nk = K >> 5;
  for (int t = 0; t < nk; t++) {
    if (t + 1 < nk) {
      GSTAGE64(cur ^ 1, (t + 1) * 32);
      asm volatile("s_waitcnt vmcnt(3)" ::: "memory");
    } else {
      asm volatile("s_waitcnt vmcnt(0)" ::: "memory");
    }
    __builtin_amdgcn_s_barrier();
    __builtin_amdgcn_sched_barrier(0);

    const char* Ar = AsB + cur * 4096;
    const char* Br = BsB + cur * 8192;
    bf16x8 a[2], b[4];
#pragma unroll
    for (int m2 = 0; m2 < 2; m2++)
      a[m2] = *(const bf16x8*)(Ar + (wr * 32 + m2 * 16 + llo) * 64 + lhi * 16);
#pragma unroll
    for (int n4 = 0; n4 < 4; n4++)
      b[n4] = *(const bf16x8*)(Br + (wc * 64 + n4 * 16 + llo) * 64 + lhi * 16);
#pragma unroll
    for (int m2 = 0; m2 < 2; m2++)
#pragma unroll
      for (int n4 = 0; n4 < 4; n4++)
        acc[m2][n4] =
            __builtin_amdgcn_mfma_f32_16x16x32_bf16(a[m2], b[n4], acc[m2][n4], 0, 0, 0);
    __builtin_amdgcn_sched_barrier(0);
    __builtin_amdgcn_s_barrier();
    cur ^= 1;
  }
#undef GSTAGE64
}

// ------------- GEMM1: kqv = x @ WkqvT^T + bkqv, scatter to K/Q/Vt ----------
// Q pre-scaled by 0.125 * log2(e) (attn works in exp2 domain).
__global__ __launch_bounds__(256) void kqv_gemm(
    const __hip_bfloat16* __restrict__ x, const __hip_bfloat16* __restrict__ WT,
    const float* __restrict__ bkqv, __hip_bfloat16* __restrict__ Qb,
    __hip_bfloat16* __restrict__ Kb, __hip_bfloat16* __restrict__ Vt) {
  __shared__ __align__(16) char As[16384];
  __shared__ __align__(16) char Bs[16384];
  const int m0 = blockIdx.y * 128, n0 = blockIdx.x * 128;
  f32x4 acc[4][4];
  gemm_mainloop_128(x, WT, 1024, m0, n0, acc, As, Bs);

  const int tid = threadIdx.x, wave = tid >> 6, lane = tid & 63;
  const int lhi = lane >> 4, llo = lane & 15;
  const int wr = wave >> 1, wc = wave & 1;
#pragma unroll
  for (int m4 = 0; m4 < 4; m4++)
#pragma unroll
    for (int n4 = 0; n4 < 4; n4++)
#pragma unroll
      for (int r = 0; r < 4; r++) {
        int mg = m0 + wr * 64 + m4 * 16 + lhi * 4 + r;
        int ng = n0 + wc * 64 + n4 * 16 + llo;
        int b = mg >> 11, s = mg & 2047;
        int h = ng / 192, f = ng % 192;
        float v = acc[m4][n4][r] + bkqv[h * 192 + f];
        int chunk = f >> 6, d = f & 63;
        size_t bh = (size_t)(b * 16 + h);
        if (chunk == 0)
          Kb[(bh * 2048 + s) * 64 + d] = __float2bfloat16(v);
        else if (chunk == 1)
          Qb[(bh * 2048 + s) * 64 + d] = __float2bfloat16(v * 0.180336880f);
        else
          Vt[(bh * 64 + d) * 2048 + s] = __float2bfloat16(v);
      }
}

// ------------------- causal flash attention, D=64 --------------------------
// UNPAIRED: 1 block = one (b,h,q-tile); nt = qt+1 kv-tiles. Grid 1024 ->
// 4 blocks/CU (LDS 40960 x 4 = 160KiB exactly). Heavy tiles dispatch first;
// each XCD owns 4 bh values (KV set 2MB < 4MB L2). Swapped QK^T softmax,
// defer-max, exp2 domain, double-buffered gload_lds staging, counted vmcnt.
__global__ __launch_bounds__(256) void attn_kernel(
    const __hip_bfloat16* __restrict__ Qb, const __hip_bfloat16* __restrict__ Kb,
    const __hip_bfloat16* __restrict__ Vt, __hip_bfloat16* __restrict__ SA) {
  __shared__ __align__(16) char lds[40960];  // Ks 2x8K | Vs 2x8K | Ps 4x2K
  const int orig = blockIdx.x;
  const int bh = (orig & 7) * 4 + ((orig >> 3) & 3);  // XCD-local bh group
  const int qt = 31 - (orig >> 5);                    // heavy first
  const int nt = qt + 1;
  const int b = bh >> 4, h = bh & 15;
  const int tid = threadIdx.x, wave = tid >> 6, lane = tid & 63;
  const int lhi = lane >> 4, llo = lane & 15;
  const int lhi4 = lhi * 4;

  const __hip_bfloat16* qp =
      Qb + ((size_t)bh * 2048 + qt * 64 + wave * 16 + llo) * 64 + lhi * 8;
  bf16x8 q0 = *(const bf16x8*)qp, q1 = *(const bf16x8*)(qp + 32);

  const char* Kg = (const char*)(Kb + (size_t)bh * 2048 * 64);
  const char* Vg = (const char*)(Vt + (size_t)bh * 64 * 2048);
  char* PsB = lds + 32768 + wave * 2048;

  f32x4 z = {0.f, 0.f, 0.f, 0.f};
  f32x4 o[4];
  float m_s = NEG_INF, l_s = 0.f;
#pragma unroll
  for (int i = 0; i < 4; i++) o[i] = z;
  const int qg = qt * 64 + wave * 16 + llo;    // masking row (lane's q)
  const int qg0 = qt * 64 + wave * 16 + lhi4;  // output row base

#define STAGE(c, k0)                                                          \
  {                                                                           \
    char* KsW = lds + (c)*8192;                                               \
    char* VsW = lds + 16384 + (c)*8192;                                       \
    _Pragma("unroll") for (int i = 0; i < 2; i++) {                           \
      int ch = i * 256 + tid;                                                 \
      int soff = (ch * 16) ^ (((ch >> 3) & 7) << 4);                          \
      gload16(Kg + (size_t)(k0)*128 + soff, KsW + (i * 256 + wave * 64) * 16);\
      int dd = ch >> 3, c8 = ch & 7;                                          \
      int boff = (c8 * 16) ^ ((dd & 7) << 4);                                 \
      gload16(Vg + (size_t)dd * 4096 + (size_t)(k0)*2 + boff,                 \
              VsW + (i * 256 + wave * 64) * 16);                              \
    }                                                                         \
  }

  STAGE(0, 0);
  int cur = 0;

  for (int T = 0; T < nt; T++) {
    if (T + 1 < nt) {
      STAGE(cur ^ 1, (T + 1) * 64);
      asm volatile("s_waitcnt vmcnt(4)" ::: "memory");
    } else {
      asm volatile("s_waitcnt vmcnt(0)" ::: "memory");
    }
    __builtin_amdgcn_s_barrier();
    __builtin_amdgcn_sched_barrier(0);

    const int k0 = T * 64;
    const bool masked = (T == nt - 1);
    const char* KsB = lds + cur * 8192;
    const char* VsB = lds + 16384 + cur * 8192;

    // ---- QK^T swapped: s[j] = C[key=j*16+lhi4+r][q=llo] ----
    f32x4 s[4] = {z, z, z, z};
#pragma unroll
    for (int j = 0; j < 4; j++) {
      const int row = j * 16 + llo;
      const int rx = (row & 7) << 4;
      bf16x8 bk0 = *(const bf16x8*)(KsB + ((row * 128 + lhi * 16) ^ rx));
      bf16x8 bk1 = *(const bf16x8*)(KsB + ((row * 128 + 64 + lhi * 16) ^ rx));
      s[j] = __builtin_amdgcn_mfma_f32_16x16x32_bf16(bk0, q0, s[j], 0, 0, 0);
      s[j] = __builtin_amdgcn_mfma_f32_16x16x32_bf16(bk1, q1, s[j], 0, 0, 0);
    }

    // ---- in-lane online softmax (lane owns q=llo; 16 scores local) ----
    if (masked) {
#pragma unroll
      for (int j = 0; j < 4; j++)
#pragma unroll
        for (int r = 0; r < 4; r++)
          if (k0 + j * 16 + lhi4 + r > qg) s[j][r] = NEG_INF;
    }
    float pmax = s[0][0];
#pragma unroll
    for (int j = 0; j < 4; j++)
#pragma unroll
      for (int r = 0; r < 4; r++) pmax = fmaxf(pmax, s[j][r]);
    pmax = fmaxf(pmax, __shfl_xor(pmax, 16));
    pmax = fmaxf(pmax, __shfl_xor(pmax, 32));
    if (!__all(pmax - m_s <= 5.0f)) {  // defer-max: rescale rarely
      const float mn = fmaxf(m_s, pmax);
      const float sc = __builtin_exp2f(m_s - mn);
      m_s = mn;
      l_s *= sc;
#pragma unroll
      for (int r = 0; r < 4; r++) {
        const float scr = __shfl(sc, lhi4 + r);
#pragma unroll
        for (int n4 = 0; n4 < 4; n4++) o[n4][r] *= scr;
      }
    }
    const int px = (llo & 7) << 4;
    float ps = 0.f;
#pragma unroll
    for (int j = 0; j < 4; j++) {
      ushort4 pw;
#pragma unroll
      for (int r = 0; r < 4; r++) {
        const float p = __builtin_exp2f(s[j][r] - m_s);
        ps += p;
        ((__hip_bfloat16*)&pw)[r] = __float2bfloat16(p);
      }
      *(ushort4*)(PsB + ((llo * 128 + j * 32 + lhi * 8) ^ px)) = pw;
    }
    l_s += ps;

    // ---- PV: o[n4] += P(16x64) . V^T ----
    {
      bf16x8 ap0 = *(const bf16x8*)(PsB + ((llo * 128 + lhi * 16) ^ px));
      bf16x8 ap1 = *(const bf16x8*)(PsB + ((llo * 128 + 64 + lhi * 16) ^ px));
#pragma unroll
      for (int n4 = 0; n4 < 4; n4++) {
        const int d = n4 * 16 + llo;
        const int dx = (d & 7) << 4;
        bf16x8 bv0 = *(const bf16x8*)(VsB + ((d * 128 + lhi * 16) ^ dx));
        bf16x8 bv1 = *(const bf16x8*)(VsB + ((d * 128 + 64 + lhi * 16) ^ dx));
        o[n4] = __builtin_amdgcn_mfma_f32_16x16x32_bf16(ap0, bv0, o[n4], 0, 0, 0);
        o[n4] = __builtin_amdgcn_mfma_f32_16x16x32_bf16(ap1, bv1, o[n4], 0, 0, 0);
      }
    }
    __builtin_amdgcn_sched_barrier(0);
    __builtin_amdgcn_s_barrier();  // all waves done reading buf[cur]
    cur ^= 1;
  }

  // epilogue
  {
    float l = l_s;
    l += __shfl_xor(l, 16);
    l += __shfl_xor(l, 32);
    const float inv = 1.f / l;
#pragma unroll
    for (int r = 0; r < 4; r++) {
      const float invr = __shfl(inv, lhi4 + r);
      const size_t ob = ((size_t)b * 2048 + qg0 + r) * 1024 + h * 64;
#pragma unroll
      for (int n4 = 0; n4 < 4; n4++)
        SA[ob + n4 * 16 + llo] = __float2bfloat16(o[n4][r] * invr);
    }
  }
#undef STAGE
}

// ------------- GEMM3: out = SA @ Wo + bo (fp32 out; 64x128 tiles) ----------
__global__ __launch_bounds__(256) void out_gemm(
    const __hip_bfloat16* __restrict__ SA, const __hip_bfloat16* __restrict__ WoT,
    const float* __restrict__ bo, float* __restrict__ out) {
  __shared__ __align__(16) char As[8192];
  __shared__ __align__(16) char Bs[16384];
  const int m0 = blockIdx.y * 64, n0 = blockIdx.x * 128;
  f32x4 acc[2][4];
  gemm_mainloop_64x128(SA, WoT, 1024, m0, n0, acc, As, Bs);

  const int tid = threadIdx.x, wave = tid >> 6, lane = tid & 63;
  const int lhi = lane >> 4, llo = lane & 15;
  const int wr = wave >> 1, wc = wave & 1;
#pragma unroll
  for (int m2 = 0; m2 < 2; m2++)
#pragma unroll
    for (int n4 = 0; n4 < 4; n4++)
#pragma unroll
      for (int r = 0; r < 4; r++) {
        int mg = m0 + wr * 32 + m2 * 16 + lhi * 4 + r;
        int ng = n0 + wc * 64 + n4 * 16 + llo;
        out[(size_t)mg * 1024 + ng] = acc[m2][n4][r] + bo[ng];
      }
}

extern "C" void kernel_launch(void* const* d_in, const int* in_sizes, int n_in,
                              void* d_out, int out_size, void* d_ws, size_t ws_size,
                              hipStream_t stream) {
  const float* x = (const float*)d_in[0];
  const float* Wkqv = (const float*)d_in[1];
  const float* bkqv = (const float*)d_in[2];
  const float* Wo = (const float*)d_in[3];
  const float* bo = (const float*)d_in[4];
  float* out = (float*)d_out;  // fp32 output (verified R5)

  char* w = (char*)d_ws;
  __hip_bfloat16* WkqvT = (__hip_bfloat16*)(w);            // 3072x1024  (6 MB)
  __hip_bfloat16* WoT = (__hip_bfloat16*)(w + 6291456);    // 1024x1024  (2 MB)
  __hip_bfloat16* Qb = (__hip_bfloat16*)(w + 8388608);     // [B][H][S][64] (8 MB)
  __hip_bfloat16* Kb = (__hip_bfloat16*)(w + 16777216);    // [B][H][S][64] (8 MB)
  __hip_bfloat16* Vt = (__hip_bfloat16*)(w + 25165824);    // [B][H][64][S] (8 MB)
  __hip_bfloat16* SAb = (__hip_bfloat16*)(w + 33554432);   // [B][S][E]     (8 MB)
  __hip_bfloat16* xb = (__hip_bfloat16*)(w + 41943040);    // [B][S][E]     (8 MB)

  prep_kernel<<<8192, 256, 0, stream>>>(x, (u16*)xb, Wkqv, (u16*)WkqvT,
                                        Wo, (u16*)WoT);
  kqv_gemm<<<dim3(24, 32), 256, 0, stream>>>(xb, WkqvT, bkqv, Qb, Kb, Vt);
  attn_kernel<<<1024, 256, 0, stream>>>(Qb, Kb, Vt, SAb);
  out_gemm<<<dim3(8, 64), 256, 0, stream>>>(SAb, WoT, bo, out);
}